// Round 9
// baseline (2994.027 us; speedup 1.0000x reference)
//
#include <hip/hip_runtime.h>
#include <hip/hip_bf16.h>

#define BATCH_N 262144

typedef __attribute__((ext_vector_type(8))) __bf16 bf16x8;
typedef __attribute__((ext_vector_type(4))) float f32x4;

// ---------------- workspace layout (bytes) ----------------
#define OFF_EPSY  0UL           // BATCH*64 bf16 = 33554432
#define OFF_W1T   33554432UL    // 64*256*64 bf16 = 2097152   W1T[i][j][k]
#define OFF_BW    35651584UL    // 64*256 float2 = 131072     {dec1_b, dec3_w}
#define OFF_E1HI  35782656UL    // 256*64 bf16                enc1T[j][k] hi
#define OFF_E1LO  35815424UL
#define OFF_E3HI  35848192UL    // 128*256 bf16               enc3T[j][k] hi
#define OFF_E3LO  35913728UL
#define OFF_NQ    35979264UL    // 64 int
#define OFF_CMASK 35979520UL    // 4096 uchar canonical mask

__device__ __forceinline__ void split_f32(float v, __bf16& hi, __bf16& lo) {
    __bf16 h = (__bf16)v;
    hi = h;
    lo = (__bf16)(v - (float)h);
}

// ---------------- prep0: canonicalize B_mask storage ----------------
__global__ __launch_bounds__(256) void cvae_prep0(
    const unsigned char* __restrict__ bm, char* __restrict__ ws)
{
    __shared__ int diag_ok;
    int t = threadIdx.x;
    if (t == 0) diag_ok = 1;
    __syncthreads();
    if (t < 64) { if (bm[t * 65] == 0) atomicAnd(&diag_ok, 0); }
    __syncthreads();
    int isbool = diag_ok;
    unsigned char* cm = (unsigned char*)(ws + OFF_CMASK);
    for (int idx = t; idx < 4096; idx += 256) {
        unsigned char v;
        if (isbool) v = bm[idx] ? 1 : 0;
        else        v = ((const unsigned int*)bm)[idx] ? 1 : 0;
        cm[idx] = v;
    }
}

// ---------------- prep: weight conversion / transpose ----------------
__global__ __launch_bounds__(256) void cvae_prep(
    const float* __restrict__ enc1_w, const float* __restrict__ enc3_w,
    const float* __restrict__ dec1_w, const float* __restrict__ dec1_b,
    const float* __restrict__ dec3_w, char* __restrict__ ws)
{
    const int bid = blockIdx.x, tid = threadIdx.x;
    const unsigned char* cm = (const unsigned char*)(ws + OFF_CMASK);
    if (bid < 8) {
        int g = bid * 256 + tid;
        int j = g >> 3, kc = (g & 7) * 8;
        __bf16* e1hi = (__bf16*)(ws + OFF_E1HI);
        __bf16* e1lo = (__bf16*)(ws + OFF_E1LO);
        bf16x8 vh, vl;
        #pragma unroll
        for (int e = 0; e < 8; ++e) {
            __bf16 h, l;
            split_f32(enc1_w[(kc + e) * 256 + j], h, l);
            vh[e] = h; vl[e] = l;
        }
        *(bf16x8*)(e1hi + j * 64 + kc) = vh;
        *(bf16x8*)(e1lo + j * 64 + kc) = vl;
    } else if (bid < 24) {
        int g = (bid - 8) * 256 + tid;
        int j = g >> 5, kc = (g & 31) * 8;
        __bf16* e3hi = (__bf16*)(ws + OFF_E3HI);
        __bf16* e3lo = (__bf16*)(ws + OFF_E3LO);
        bf16x8 vh, vl;
        #pragma unroll
        for (int e = 0; e < 8; ++e) {
            __bf16 h, l;
            split_f32(enc3_w[(kc + e) * 128 + j], h, l);
            vh[e] = h; vl[e] = l;
        }
        *(bf16x8*)(e3hi + j * 256 + kc) = vh;
        *(bf16x8*)(e3lo + j * 256 + kc) = vl;
    } else if (bid < 536) {
        int g = (bid - 24) * 256 + tid;
        int i = g >> 11;
        int rem = g & 2047;
        int j = rem >> 3, kc = (rem & 7) * 8;
        __bf16* w1t = (__bf16*)(ws + OFF_W1T);
        bf16x8 v;
        #pragma unroll
        for (int e = 0; e < 8; ++e) {
            int k = kc + e;
            float m = cm[k * 64 + i] ? 1.0f : 0.0f;  // B_mask[k][i]
            v[e] = (__bf16)(dec1_w[(i * 64 + k) * 256 + j] * m);
        }
        *(bf16x8*)(w1t + ((size_t)(i * 256 + j)) * 64 + kc) = v;
    } else if (bid < 600) {
        int g = (bid - 536) * 256 + tid;
        float2* bw = (float2*)(ws + OFF_BW);
        float2 p; p.x = dec1_b[g]; p.y = dec3_w[g];
        bw[g] = p;
    } else {
        if (tid < 64) {
            int any = 0;
            for (int k = 32; k < 64; ++k) any |= (int)cm[k * 64 + tid];
            ((int*)(ws + OFF_NQ))[tid] = any ? 2 : 1;
        }
    }
}

// ---------------- encoder (R1 v1, proven) ----------------
__global__ __launch_bounds__(256, 2) void cvae_encoder(
    const float* __restrict__ x, const float* __restrict__ eps,
    const float* __restrict__ enc1_b, const float* __restrict__ enc3_b,
    float* __restrict__ out, char* __restrict__ ws)
{
    __shared__ float hbuf[16384];
    const int tid = threadIdx.x;
    const int w = tid >> 6, l = tid & 63;
    const int lr = l & 15, lg = l >> 4;
    const size_t rowbase = (size_t)blockIdx.x * 64 + w * 16;
    const size_t arow = rowbase + lr;

    const __bf16* e1hi = (const __bf16*)(ws + OFF_E1HI);
    const __bf16* e1lo = (const __bf16*)(ws + OFF_E1LO);
    const __bf16* e3hi = (const __bf16*)(ws + OFF_E3HI);
    const __bf16* e3lo = (const __bf16*)(ws + OFF_E3LO);
    __bf16* epsy = (__bf16*)(ws + OFF_EPSY);
    float* muo = out + (size_t)BATCH_N * 64;
    float* lvo = out + (size_t)BATCH_N * 128;

    bf16x8 xhi[2], xlo[2];
    #pragma unroll
    for (int q = 0; q < 2; ++q) {
        const float* xp = x + arow * 64 + q * 32 + lg * 8;
        #pragma unroll
        for (int e = 0; e < 8; ++e) {
            __bf16 h, lo2; split_f32(xp[e], h, lo2);
            xhi[q][e] = h; xlo[q][e] = lo2;
        }
    }
    float* hw = hbuf + w * 4096;

    for (int t = 0; t < 16; ++t) {
        int j = t * 16 + lr;
        bf16x8 bh0 = *(const bf16x8*)(e1hi + j * 64 + lg * 8);
        bf16x8 bh1 = *(const bf16x8*)(e1hi + j * 64 + 32 + lg * 8);
        bf16x8 bl0 = *(const bf16x8*)(e1lo + j * 64 + lg * 8);
        bf16x8 bl1 = *(const bf16x8*)(e1lo + j * 64 + 32 + lg * 8);
        float b = enc1_b[j];
        f32x4 acc = {b, b, b, b};
        acc = __builtin_amdgcn_mfma_f32_16x16x32_bf16(xhi[0], bh0, acc, 0, 0, 0);
        acc = __builtin_amdgcn_mfma_f32_16x16x32_bf16(xhi[1], bh1, acc, 0, 0, 0);
        acc = __builtin_amdgcn_mfma_f32_16x16x32_bf16(xlo[0], bh0, acc, 0, 0, 0);
        acc = __builtin_amdgcn_mfma_f32_16x16x32_bf16(xlo[1], bh1, acc, 0, 0, 0);
        acc = __builtin_amdgcn_mfma_f32_16x16x32_bf16(xhi[0], bl0, acc, 0, 0, 0);
        acc = __builtin_amdgcn_mfma_f32_16x16x32_bf16(xhi[1], bl1, acc, 0, 0, 0);
        #pragma unroll
        for (int e = 0; e < 4; ++e) {
            int wr = lg * 4 + e;
            hw[(wr * 256 + j) ^ ((wr & 7) << 2)] = fmaxf(acc[e], 0.0f);
        }
    }

    bf16x8 hhi[8], hlo[8];
    #pragma unroll
    for (int q = 0; q < 8; ++q) {
        int k0 = q * 32 + lg * 8;
        int w0 = (lr * 256 + k0) ^ ((lr & 7) << 2);
        int w1 = (lr * 256 + k0 + 4) ^ ((lr & 7) << 2);
        f32x4 a = *(const f32x4*)(hw + w0);
        f32x4 c = *(const f32x4*)(hw + w1);
        #pragma unroll
        for (int e = 0; e < 4; ++e) {
            __bf16 h, lo2;
            split_f32(a[e], h, lo2); hhi[q][e] = h;     hlo[q][e] = lo2;
            split_f32(c[e], h, lo2); hhi[q][4 + e] = h; hlo[q][4 + e] = lo2;
        }
    }

    f32x4 macc[4];
    #pragma unroll
    for (int t2 = 0; t2 < 8; ++t2) {
        int j2 = t2 * 16 + lr;
        float b2 = enc3_b[j2];
        f32x4 acc = {b2, b2, b2, b2};
        #pragma unroll
        for (int q = 0; q < 8; ++q) {
            bf16x8 bh = *(const bf16x8*)(e3hi + j2 * 256 + q * 32 + lg * 8);
            bf16x8 bl = *(const bf16x8*)(e3lo + j2 * 256 + q * 32 + lg * 8);
            acc = __builtin_amdgcn_mfma_f32_16x16x32_bf16(hhi[q], bh, acc, 0, 0, 0);
            acc = __builtin_amdgcn_mfma_f32_16x16x32_bf16(hlo[q], bh, acc, 0, 0, 0);
            acc = __builtin_amdgcn_mfma_f32_16x16x32_bf16(hhi[q], bl, acc, 0, 0, 0);
        }
        if (t2 < 4) {
            macc[t2] = acc;
            #pragma unroll
            for (int e = 0; e < 4; ++e)
                muo[(rowbase + lg * 4 + e) * 64 + j2] = acc[e];
        } else {
            int jm = j2 - 64;
            #pragma unroll
            for (int e = 0; e < 4; ++e) {
                size_t r = rowbase + lg * 4 + e;
                float lv = acc[e];
                lvo[r * 64 + jm] = lv;
                float ey = macc[t2 - 4][e] +
                           exp2f(lv * 0.72134752044448170f) * eps[r * 64 + jm];
                epsy[r * 64 + jm] = (__bf16)ey;
            }
        }
    }
}

// ---------------- decoder inner loop (v9: full unroll + scalar fmaf) ----------------
template<int NQ>
__device__ __forceinline__ void dec_accum(
    const __bf16* __restrict__ wp, const float2* __restrict__ bwp,
    const bf16x8 (&af)[8][2], float (&psum)[8][4])
{
    #pragma unroll
    for (int t = 0; t < 16; ++t) {
        bf16x8 b0 = *(const bf16x8*)(wp + (size_t)t * 1024);
        bf16x8 b1;
        if (NQ == 2) b1 = *(const bf16x8*)(wp + (size_t)t * 1024 + 32);
        float2 bwv = bwp[t * 16];
        f32x4 bias = {bwv.x, bwv.x, bwv.x, bwv.x};   // dec1_b folded into C
        #pragma unroll
        for (int r = 0; r < 8; ++r) {
            f32x4 acc = __builtin_amdgcn_mfma_f32_16x16x32_bf16(af[r][0], b0, bias, 0, 0, 0);
            if (NQ == 2)
                acc = __builtin_amdgcn_mfma_f32_16x16x32_bf16(af[r][1], b1, acc, 0, 0, 0);
            psum[r][0] = fmaf(fmaxf(acc[0], 0.0f), bwv.y, psum[r][0]);
            psum[r][1] = fmaf(fmaxf(acc[1], 0.0f), bwv.y, psum[r][1]);
            psum[r][2] = fmaf(fmaxf(acc[2], 0.0f), bwv.y, psum[r][2]);
            psum[r][3] = fmaf(fmaxf(acc[3], 0.0f), bwv.y, psum[r][3]);
        }
    }
}

// ---------------- decoder: full-unroll core, 256-reg budget (no AGPR split) ----------------
__global__ __launch_bounds__(256, 2) void cvae_decoder(
    const char* __restrict__ ws, const float* __restrict__ dec3_b,
    float* __restrict__ out)
{
    __shared__ float xt[128 * 68];
    const int tid = threadIdx.x;
    const int w = tid >> 6, l = tid & 63;
    const int lr = l & 15, lg = l >> 4;
    const size_t rb = (size_t)blockIdx.x * 128;
    const __bf16* epsy = (const __bf16*)(ws + OFF_EPSY);
    const __bf16* w1t  = (const __bf16*)(ws + OFF_W1T);
    const float2* bw   = (const float2*)(ws + OFF_BW);
    const int* nqt     = (const int*)(ws + OFF_NQ);

    // A-fragments: 128 rows of eps_y, reused for all 64 i
    bf16x8 af[8][2];
    #pragma unroll
    for (int r = 0; r < 8; ++r)
        #pragma unroll
        for (int q = 0; q < 2; ++q)
            af[r][q] = *(const bf16x8*)(epsy + (rb + r * 16 + lr) * 64 + q * 32 + lg * 8);

    for (int ii = 0; ii < 16; ++ii) {
        const int i = ii * 4 + w;               // interleaved for nq balance
        const __bf16* wp = w1t + ((size_t)i * 256 + lr) * 64 + lg * 8;
        const float2* bwp = bw + i * 256 + lr;
        float psum[8][4];
        #pragma unroll
        for (int r = 0; r < 8; ++r) {
            psum[r][0] = 0.f; psum[r][1] = 0.f; psum[r][2] = 0.f; psum[r][3] = 0.f;
        }
        if (nqt[i] == 2) dec_accum<2>(wp, bwp, af, psum);
        else             dec_accum<1>(wp, bwp, af, psum);

        const float b3 = dec3_b[i];
        #pragma unroll
        for (int r = 0; r < 8; ++r)
            #pragma unroll
            for (int e = 0; e < 4; ++e) {
                float v = psum[r][e];
                v += __shfl_xor(v, 1);
                v += __shfl_xor(v, 2);
                v += __shfl_xor(v, 4);
                v += __shfl_xor(v, 8);
                psum[r][e] = v + b3;
            }
        if (lr == (i & 15)) {
            #pragma unroll
            for (int r = 0; r < 8; ++r)
                #pragma unroll
                for (int e = 0; e < 4; ++e)
                    xt[(r * 16 + lg * 4 + e) * 68 + i] = psum[r][e];
        }
    }
    __syncthreads();

    float* yr = out + (size_t)BATCH_N * 192;
    #pragma unroll
    for (int c = 0; c < 8; ++c) {
        int idx = c * 1024 + tid * 4;
        int row = idx >> 6, col = idx & 63;
        f32x4 v = *(const f32x4*)(xt + row * 68 + col);
        *(f32x4*)(out + (rb + row) * 64 + col) = v;
        *(f32x4*)(yr + (rb + row) * 128 + col) = v;
        f32x4 z = {0.f, 0.f, 0.f, 0.f};
        *(f32x4*)(yr + (rb + row) * 128 + 64 + col) = z;
    }
}

extern "C" void kernel_launch(void* const* d_in, const int* in_sizes, int n_in,
                              void* d_out, int out_size, void* d_ws, size_t ws_size,
                              hipStream_t stream)
{
    (void)in_sizes; (void)n_in; (void)out_size; (void)ws_size;
    const float* x      = (const float*)d_in[0];
    const float* eps    = (const float*)d_in[1];
    const float* enc1_w = (const float*)d_in[2];
    const float* enc1_b = (const float*)d_in[3];
    const float* enc3_w = (const float*)d_in[4];
    const float* enc3_b = (const float*)d_in[5];
    const float* dec1_w = (const float*)d_in[6];
    const float* dec1_b = (const float*)d_in[7];
    const float* dec3_w = (const float*)d_in[8];
    const float* dec3_b = (const float*)d_in[9];
    const unsigned char* bmask = (const unsigned char*)d_in[10];
    float* out = (float*)d_out;
    char* ws = (char*)d_ws;

    hipLaunchKernelGGL(cvae_prep0, dim3(1), dim3(256), 0, stream, bmask, ws);
    hipLaunchKernelGGL(cvae_prep, dim3(601), dim3(256), 0, stream,
                       enc1_w, enc3_w, dec1_w, dec1_b, dec3_w, ws);
    hipLaunchKernelGGL(cvae_encoder, dim3(BATCH_N / 64), dim3(256), 0, stream,
                       x, eps, enc1_b, enc3_b, out, ws);
    hipLaunchKernelGGL(cvae_decoder, dim3(BATCH_N / 128), dim3(256), 0, stream,
                       ws, dec3_b, out);
}

// Round 10
// 912.916 us; speedup vs baseline: 3.2796x; 3.2796x over previous
//
#include <hip/hip_runtime.h>
#include <hip/hip_bf16.h>

#define BATCH_N 262144

typedef __attribute__((ext_vector_type(8))) __bf16 bf16x8;
typedef __attribute__((ext_vector_type(4))) float f32x4;
typedef __attribute__((ext_vector_type(2))) float f32x2;

// ---------------- workspace layout (bytes) ----------------
#define OFF_EPSY  0UL           // BATCH*64 bf16 = 33554432
#define OFF_W1T   33554432UL    // 64*256*64 bf16 = 2097152   W1T[i][j][k]
#define OFF_BW    35651584UL    // 64*256 float2 = 131072     {dec1_b, dec3_w}
#define OFF_E1HI  35782656UL    // 256*64 bf16                enc1T[j][k] hi
#define OFF_E1LO  35815424UL
#define OFF_E3HI  35848192UL    // 128*256 bf16               enc3T[j][k] hi
#define OFF_E3LO  35913728UL
#define OFF_NQ    35979264UL    // 64 int
#define OFF_CMASK 35979520UL    // 4096 uchar canonical mask

__device__ __forceinline__ void split_f32(float v, __bf16& hi, __bf16& lo) {
    __bf16 h = (__bf16)v;
    hi = h;
    lo = (__bf16)(v - (float)h);
}

// ---------------- prep0: canonicalize B_mask storage ----------------
__global__ __launch_bounds__(256) void cvae_prep0(
    const unsigned char* __restrict__ bm, char* __restrict__ ws)
{
    __shared__ int diag_ok;
    int t = threadIdx.x;
    if (t == 0) diag_ok = 1;
    __syncthreads();
    if (t < 64) { if (bm[t * 65] == 0) atomicAnd(&diag_ok, 0); }
    __syncthreads();
    int isbool = diag_ok;
    unsigned char* cm = (unsigned char*)(ws + OFF_CMASK);
    for (int idx = t; idx < 4096; idx += 256) {
        unsigned char v;
        if (isbool) v = bm[idx] ? 1 : 0;
        else        v = ((const unsigned int*)bm)[idx] ? 1 : 0;
        cm[idx] = v;
    }
}

// ---------------- prep: weight conversion / transpose ----------------
__global__ __launch_bounds__(256) void cvae_prep(
    const float* __restrict__ enc1_w, const float* __restrict__ enc3_w,
    const float* __restrict__ dec1_w, const float* __restrict__ dec1_b,
    const float* __restrict__ dec3_w, char* __restrict__ ws)
{
    const int bid = blockIdx.x, tid = threadIdx.x;
    const unsigned char* cm = (const unsigned char*)(ws + OFF_CMASK);
    if (bid < 8) {
        int g = bid * 256 + tid;
        int j = g >> 3, kc = (g & 7) * 8;
        __bf16* e1hi = (__bf16*)(ws + OFF_E1HI);
        __bf16* e1lo = (__bf16*)(ws + OFF_E1LO);
        bf16x8 vh, vl;
        #pragma unroll
        for (int e = 0; e < 8; ++e) {
            __bf16 h, l;
            split_f32(enc1_w[(kc + e) * 256 + j], h, l);
            vh[e] = h; vl[e] = l;
        }
        *(bf16x8*)(e1hi + j * 64 + kc) = vh;
        *(bf16x8*)(e1lo + j * 64 + kc) = vl;
    } else if (bid < 24) {
        int g = (bid - 8) * 256 + tid;
        int j = g >> 5, kc = (g & 31) * 8;
        __bf16* e3hi = (__bf16*)(ws + OFF_E3HI);
        __bf16* e3lo = (__bf16*)(ws + OFF_E3LO);
        bf16x8 vh, vl;
        #pragma unroll
        for (int e = 0; e < 8; ++e) {
            __bf16 h, l;
            split_f32(enc3_w[(kc + e) * 128 + j], h, l);
            vh[e] = h; vl[e] = l;
        }
        *(bf16x8*)(e3hi + j * 256 + kc) = vh;
        *(bf16x8*)(e3lo + j * 256 + kc) = vl;
    } else if (bid < 536) {
        int g = (bid - 24) * 256 + tid;
        int i = g >> 11;
        int rem = g & 2047;
        int j = rem >> 3, kc = (rem & 7) * 8;
        __bf16* w1t = (__bf16*)(ws + OFF_W1T);
        bf16x8 v;
        #pragma unroll
        for (int e = 0; e < 8; ++e) {
            int k = kc + e;
            float m = cm[k * 64 + i] ? 1.0f : 0.0f;  // B_mask[k][i]
            v[e] = (__bf16)(dec1_w[(i * 64 + k) * 256 + j] * m);
        }
        *(bf16x8*)(w1t + ((size_t)(i * 256 + j)) * 64 + kc) = v;
    } else if (bid < 600) {
        int g = (bid - 536) * 256 + tid;
        float2* bw = (float2*)(ws + OFF_BW);
        float2 p; p.x = dec1_b[g]; p.y = dec3_w[g];
        bw[g] = p;
    } else {
        if (tid < 64) {
            int any = 0;
            for (int k = 32; k < 64; ++k) any |= (int)cm[k * 64 + tid];
            ((int*)(ws + OFF_NQ))[tid] = any ? 2 : 1;
        }
    }
}

// ---------------- encoder (R1 v1, proven) ----------------
__global__ __launch_bounds__(256, 2) void cvae_encoder(
    const float* __restrict__ x, const float* __restrict__ eps,
    const float* __restrict__ enc1_b, const float* __restrict__ enc3_b,
    float* __restrict__ out, char* __restrict__ ws)
{
    __shared__ float hbuf[16384];
    const int tid = threadIdx.x;
    const int w = tid >> 6, l = tid & 63;
    const int lr = l & 15, lg = l >> 4;
    const size_t rowbase = (size_t)blockIdx.x * 64 + w * 16;
    const size_t arow = rowbase + lr;

    const __bf16* e1hi = (const __bf16*)(ws + OFF_E1HI);
    const __bf16* e1lo = (const __bf16*)(ws + OFF_E1LO);
    const __bf16* e3hi = (const __bf16*)(ws + OFF_E3HI);
    const __bf16* e3lo = (const __bf16*)(ws + OFF_E3LO);
    __bf16* epsy = (__bf16*)(ws + OFF_EPSY);
    float* muo = out + (size_t)BATCH_N * 64;
    float* lvo = out + (size_t)BATCH_N * 128;

    bf16x8 xhi[2], xlo[2];
    #pragma unroll
    for (int q = 0; q < 2; ++q) {
        const float* xp = x + arow * 64 + q * 32 + lg * 8;
        #pragma unroll
        for (int e = 0; e < 8; ++e) {
            __bf16 h, lo2; split_f32(xp[e], h, lo2);
            xhi[q][e] = h; xlo[q][e] = lo2;
        }
    }
    float* hw = hbuf + w * 4096;

    for (int t = 0; t < 16; ++t) {
        int j = t * 16 + lr;
        bf16x8 bh0 = *(const bf16x8*)(e1hi + j * 64 + lg * 8);
        bf16x8 bh1 = *(const bf16x8*)(e1hi + j * 64 + 32 + lg * 8);
        bf16x8 bl0 = *(const bf16x8*)(e1lo + j * 64 + lg * 8);
        bf16x8 bl1 = *(const bf16x8*)(e1lo + j * 64 + 32 + lg * 8);
        float b = enc1_b[j];
        f32x4 acc = {b, b, b, b};
        acc = __builtin_amdgcn_mfma_f32_16x16x32_bf16(xhi[0], bh0, acc, 0, 0, 0);
        acc = __builtin_amdgcn_mfma_f32_16x16x32_bf16(xhi[1], bh1, acc, 0, 0, 0);
        acc = __builtin_amdgcn_mfma_f32_16x16x32_bf16(xlo[0], bh0, acc, 0, 0, 0);
        acc = __builtin_amdgcn_mfma_f32_16x16x32_bf16(xlo[1], bh1, acc, 0, 0, 0);
        acc = __builtin_amdgcn_mfma_f32_16x16x32_bf16(xhi[0], bl0, acc, 0, 0, 0);
        acc = __builtin_amdgcn_mfma_f32_16x16x32_bf16(xhi[1], bl1, acc, 0, 0, 0);
        #pragma unroll
        for (int e = 0; e < 4; ++e) {
            int wr = lg * 4 + e;
            hw[(wr * 256 + j) ^ ((wr & 7) << 2)] = fmaxf(acc[e], 0.0f);
        }
    }

    bf16x8 hhi[8], hlo[8];
    #pragma unroll
    for (int q = 0; q < 8; ++q) {
        int k0 = q * 32 + lg * 8;
        int w0 = (lr * 256 + k0) ^ ((lr & 7) << 2);
        int w1 = (lr * 256 + k0 + 4) ^ ((lr & 7) << 2);
        f32x4 a = *(const f32x4*)(hw + w0);
        f32x4 c = *(const f32x4*)(hw + w1);
        #pragma unroll
        for (int e = 0; e < 4; ++e) {
            __bf16 h, lo2;
            split_f32(a[e], h, lo2); hhi[q][e] = h;     hlo[q][e] = lo2;
            split_f32(c[e], h, lo2); hhi[q][4 + e] = h; hlo[q][4 + e] = lo2;
        }
    }

    f32x4 macc[4];
    #pragma unroll
    for (int t2 = 0; t2 < 8; ++t2) {
        int j2 = t2 * 16 + lr;
        float b2 = enc3_b[j2];
        f32x4 acc = {b2, b2, b2, b2};
        #pragma unroll
        for (int q = 0; q < 8; ++q) {
            bf16x8 bh = *(const bf16x8*)(e3hi + j2 * 256 + q * 32 + lg * 8);
            bf16x8 bl = *(const bf16x8*)(e3lo + j2 * 256 + q * 32 + lg * 8);
            acc = __builtin_amdgcn_mfma_f32_16x16x32_bf16(hhi[q], bh, acc, 0, 0, 0);
            acc = __builtin_amdgcn_mfma_f32_16x16x32_bf16(hlo[q], bh, acc, 0, 0, 0);
            acc = __builtin_amdgcn_mfma_f32_16x16x32_bf16(hhi[q], bl, acc, 0, 0, 0);
        }
        if (t2 < 4) {
            macc[t2] = acc;
            #pragma unroll
            for (int e = 0; e < 4; ++e)
                muo[(rowbase + lg * 4 + e) * 64 + j2] = acc[e];
        } else {
            int jm = j2 - 64;
            #pragma unroll
            for (int e = 0; e < 4; ++e) {
                size_t r = rowbase + lg * 4 + e;
                float lv = acc[e];
                lvo[r * 64 + jm] = lv;
                float ey = macc[t2 - 4][e] +
                           exp2f(lv * 0.72134752044448170f) * eps[r * 64 + jm];
                epsy[r * 64 + jm] = (__bf16)ey;
            }
        }
    }
}

// ---------------- decoder inner loop (R8-proven: full unroll, static indexing,
//                  vector f32x2 psum) + high wave priority during compute ----------------
template<int NQ>
__device__ __forceinline__ void dec_accum(
    const __bf16* __restrict__ wp, const float2* __restrict__ bwp,
    const bf16x8 (&af)[8][2], f32x2 (&ps)[8][2])
{
    __builtin_amdgcn_s_setprio(1);   // favor compute-phase waves over epilogue-phase waves
    #pragma unroll
    for (int t = 0; t < 16; ++t) {
        bf16x8 b0 = *(const bf16x8*)(wp + (size_t)t * 1024);
        bf16x8 b1;
        if (NQ == 2) b1 = *(const bf16x8*)(wp + (size_t)t * 1024 + 32);
        float2 bwv = bwp[t * 16];
        f32x4 bias = {bwv.x, bwv.x, bwv.x, bwv.x};   // dec1_b folded into C
        f32x2 wv; wv[0] = bwv.y; wv[1] = bwv.y;
        #pragma unroll
        for (int r = 0; r < 8; ++r) {
            f32x4 acc = __builtin_amdgcn_mfma_f32_16x16x32_bf16(af[r][0], b0, bias, 0, 0, 0);
            if (NQ == 2)
                acc = __builtin_amdgcn_mfma_f32_16x16x32_bf16(af[r][1], b1, acc, 0, 0, 0);
            f32x2 p0; p0[0] = fmaxf(acc[0], 0.f); p0[1] = fmaxf(acc[1], 0.f);
            f32x2 p1; p1[0] = fmaxf(acc[2], 0.f); p1[1] = fmaxf(acc[3], 0.f);
            ps[r][0] += p0 * wv;   // contracts to (pk_)fma; same per-element math
            ps[r][1] += p1 * wv;
        }
    }
    __builtin_amdgcn_s_setprio(0);
}

// ---------------- decoder: R8 structure (256,3), dynamic nq dispatch ----------------
__global__ __launch_bounds__(256, 3) void cvae_decoder(
    const char* __restrict__ ws, const float* __restrict__ dec3_b,
    float* __restrict__ out)
{
    __shared__ float xt[128 * 68];
    const int tid = threadIdx.x;
    const int w = tid >> 6, l = tid & 63;
    const int lr = l & 15, lg = l >> 4;
    const size_t rb = (size_t)blockIdx.x * 128;
    const __bf16* epsy = (const __bf16*)(ws + OFF_EPSY);
    const __bf16* w1t  = (const __bf16*)(ws + OFF_W1T);
    const float2* bw   = (const float2*)(ws + OFF_BW);
    const int* nqt     = (const int*)(ws + OFF_NQ);

    // A-fragments: 128 rows of eps_y, reused for all 64 i
    bf16x8 af[8][2];
    #pragma unroll
    for (int r = 0; r < 8; ++r)
        #pragma unroll
        for (int q = 0; q < 2; ++q)
            af[r][q] = *(const bf16x8*)(epsy + (rb + r * 16 + lr) * 64 + q * 32 + lg * 8);

    for (int ii = 0; ii < 16; ++ii) {
        const int i = ii * 4 + w;               // interleaved for nq balance
        const __bf16* wp = w1t + ((size_t)i * 256 + lr) * 64 + lg * 8;
        const float2* bwp = bw + i * 256 + lr;
        f32x2 ps[8][2];
        #pragma unroll
        for (int r = 0; r < 8; ++r) {
            ps[r][0] = (f32x2){0.f, 0.f};
            ps[r][1] = (f32x2){0.f, 0.f};
        }
        if (nqt[i] == 2) dec_accum<2>(wp, bwp, af, ps);
        else             dec_accum<1>(wp, bwp, af, ps);

        const float b3 = dec3_b[i];
        float pv[8][4];
        #pragma unroll
        for (int r = 0; r < 8; ++r) {
            pv[r][0] = ps[r][0][0]; pv[r][1] = ps[r][0][1];
            pv[r][2] = ps[r][1][0]; pv[r][3] = ps[r][1][1];
        }
        #pragma unroll
        for (int r = 0; r < 8; ++r)
            #pragma unroll
            for (int e = 0; e < 4; ++e) {
                float v = pv[r][e];
                v += __shfl_xor(v, 1);
                v += __shfl_xor(v, 2);
                v += __shfl_xor(v, 4);
                v += __shfl_xor(v, 8);
                pv[r][e] = v + b3;
            }
        if (lr == (i & 15)) {
            #pragma unroll
            for (int r = 0; r < 8; ++r)
                #pragma unroll
                for (int e = 0; e < 4; ++e)
                    xt[(r * 16 + lg * 4 + e) * 68 + i] = pv[r][e];
        }
    }
    __syncthreads();

    float* yr = out + (size_t)BATCH_N * 192;
    #pragma unroll
    for (int c = 0; c < 8; ++c) {
        int idx = c * 1024 + tid * 4;
        int row = idx >> 6, col = idx & 63;
        f32x4 v = *(const f32x4*)(xt + row * 68 + col);
        *(f32x4*)(out + (rb + row) * 64 + col) = v;
        *(f32x4*)(yr + (rb + row) * 128 + col) = v;
        f32x4 z = {0.f, 0.f, 0.f, 0.f};
        *(f32x4*)(yr + (rb + row) * 128 + 64 + col) = z;
    }
}

extern "C" void kernel_launch(void* const* d_in, const int* in_sizes, int n_in,
                              void* d_out, int out_size, void* d_ws, size_t ws_size,
                              hipStream_t stream)
{
    (void)in_sizes; (void)n_in; (void)out_size; (void)ws_size;
    const float* x      = (const float*)d_in[0];
    const float* eps    = (const float*)d_in[1];
    const float* enc1_w = (const float*)d_in[2];
    const float* enc1_b = (const float*)d_in[3];
    const float* enc3_w = (const float*)d_in[4];
    const float* enc3_b = (const float*)d_in[5];
    const float* dec1_w = (const float*)d_in[6];
    const float* dec1_b = (const float*)d_in[7];
    const float* dec3_w = (const float*)d_in[8];
    const float* dec3_b = (const float*)d_in[9];
    const unsigned char* bmask = (const unsigned char*)d_in[10];
    float* out = (float*)d_out;
    char* ws = (char*)d_ws;

    hipLaunchKernelGGL(cvae_prep0, dim3(1), dim3(256), 0, stream, bmask, ws);
    hipLaunchKernelGGL(cvae_prep, dim3(601), dim3(256), 0, stream,
                       enc1_w, enc3_w, dec1_w, dec1_b, dec3_w, ws);
    hipLaunchKernelGGL(cvae_encoder, dim3(BATCH_N / 64), dim3(256), 0, stream,
                       x, eps, enc1_b, enc3_b, out, ws);
    hipLaunchKernelGGL(cvae_decoder, dim3(BATCH_N / 128), dim3(256), 0, stream,
                       ws, dec3_b, out);
}